// Round 4
// baseline (860.067 us; speedup 1.0000x reference)
//
#include <hip/hip_runtime.h>
#include <math.h>

// Problem constants (from reference)
constexpr int T_ = 131072;
constexpr int E_ = 512;
constexpr int H_ = 512;
constexpr int K_ = 1024;
constexpr int L_ = 128;

typedef __attribute__((ext_vector_type(4))) float f32x4;

// Workspace layout (element offsets; floats unless noted)
constexpr size_t OFF_V      = 0;                     // 512 f
constexpr size_t OFF_ALPHA  = 512;                   // 131072 f (reused as attn partials)
constexpr size_t OFF_HIST1  = OFF_ALPHA + T_;        // 65536 u32
constexpr size_t OFF_HIST2  = OFF_HIST1 + 65536;     // 65536 u32
constexpr size_t OFF_CNT    = OFF_HIST2 + 65536;     // 2 u32
constexpr size_t OFF_INFO   = OFF_CNT + 2;           // 8 u32
constexpr size_t OFF_CHUNK1 = OFF_INFO + 8;          // 512 u32 (hist1 chunk sums, 128 bins/chunk)
constexpr size_t OFF_CHUNK2 = OFF_CHUNK1 + 512;      // 512 u32
constexpr size_t OFF_VALS   = OFF_CHUNK2 + 512;      // 1024 f
constexpr size_t OFF_IDX    = OFF_VALS + K_;         // 1024 i32
constexpr size_t OFF_GI     = OFF_IDX + K_;          // 1536 f
constexpr size_t OFF_GH     = OFF_GI + 3 * H_;       // 1536 f

// Zeroed-per-call contiguous region: hist1..chunk2
constexpr int ZERO_N = 65536 + 65536 + 2 + 8 + 512 + 512;  // 132166 u32

// Output layout: score(1) | h_new(512) | vs_new((T+1)*512) | hs_new((T+1)*512)
constexpr size_t OUT_VS = 513;
constexpr size_t OUT_HS = 513 + (size_t)(T_ + 1) * E_;

__device__ __forceinline__ unsigned fkey(float f) {
    unsigned u = __float_as_uint(f);
    return (u & 0x80000000u) ? ~u : (u | 0x80000000u);  // ascending key == ascending float
}

// Last block: v = mean(emb[topic]) (two 512-thread halves, deterministic order).
// Other blocks: zero hist1..chunk2 (ZERO_N u32, contiguous).
__global__ __launch_bounds__(1024) void k_init(const int* __restrict__ topic,
                                               const float* __restrict__ emb,
                                               float* __restrict__ ws_v,
                                               unsigned* __restrict__ zero_base,
                                               float* __restrict__ out) {
    if (blockIdx.x == gridDim.x - 1) {
        __shared__ float part[512];
        int t = threadIdx.x;
        int e = t & 511, g = t >> 9;       // g in {0,1}
        float s = 0.f;
        #pragma unroll 8
        for (int l = g * 64; l < g * 64 + 64; ++l) {
            int tp = topic[l];
            s += emb[(size_t)tp * E_ + e];
        }
        if (g == 1) part[e] = s;
        __syncthreads();
        if (g == 0) {
            float v = (s + part[e]) * (1.0f / L_);
            ws_v[e] = v;
            out[OUT_VS + (size_t)T_ * E_ + e] = v;  // vs_new last row
        }
    } else {
        int i = blockIdx.x * blockDim.x + threadIdx.x;
        if (i < ZERO_N) zero_base[i] = 0u;
    }
}

// Mega kernel: fused {vs copy + alpha dot + hist1/chunk1} and {hs copy}.
// NT float4 streams; misaligned output rows realigned via shuffle-rotate.
__global__ __launch_bounds__(256) void k_mega(const float* __restrict__ vs,
                                              const float* __restrict__ hs,
                                              const float* __restrict__ ws_v,
                                              float* __restrict__ alpha,
                                              unsigned* __restrict__ hist1,
                                              unsigned* __restrict__ chunk1,
                                              float* __restrict__ out) {
    int wave = threadIdx.x >> 6, lane = threadIdx.x & 63;
    int b = blockIdx.x;
    bool is_vs = b < (T_ / 4);
    int row = (is_vs ? b : b - T_ / 4) * 4 + wave;
    const f32x4* src4 = (const f32x4*)((is_vs ? vs : hs) + (size_t)row * E_);
    f32x4 a0 = __builtin_nontemporal_load(&src4[lane]);
    f32x4 a1 = __builtin_nontemporal_load(&src4[lane + 64]);
    if (is_vs) {
        const f32x4* v4 = (const f32x4*)ws_v;
        f32x4 b0 = v4[lane];
        f32x4 b1 = v4[lane + 64];
        float dot = 0.f;
        dot = fmaf(a0.x, b0.x, dot); dot = fmaf(a0.y, b0.y, dot);
        dot = fmaf(a0.z, b0.z, dot); dot = fmaf(a0.w, b0.w, dot);
        dot = fmaf(a1.x, b1.x, dot); dot = fmaf(a1.y, b1.y, dot);
        dot = fmaf(a1.z, b1.z, dot); dot = fmaf(a1.w, b1.w, dot);
        #pragma unroll
        for (int m = 32; m; m >>= 1) dot += __shfl_xor(dot, m, 64);
        if (lane == 0) {
            alpha[row] = dot;
            unsigned bin = fkey(dot) >> 16;
            atomicAdd(&hist1[bin], 1u);
            atomicAdd(&chunk1[bin >> 7], 1u);
        }
    }
    // Shuffle-rotate realignment
    int nl = (lane + 1) & 63;
    float n0x = __shfl(a0.x, nl, 64), n0y = __shfl(a0.y, nl, 64), n0z = __shfl(a0.z, nl, 64);
    float n1x = __shfl(a1.x, nl, 64), n1y = __shfl(a1.y, nl, 64), n1z = __shfl(a1.z, nl, 64);
    float* dst = out + (is_vs ? OUT_VS : OUT_HS) + (size_t)row * E_;
    f32x4* d4 = (f32x4*)(dst + 3);            // 16B-aligned
    bool last = (lane == 63);
    f32x4 lo;
    lo.x = a0.w;
    lo.y = last ? n1x : n0x;   // lane 63: e[256..258] = a1.xyz of lane 0
    lo.z = last ? n1y : n0y;
    lo.w = last ? n1z : n0z;
    __builtin_nontemporal_store(lo, &d4[lane]);
    if (!last) {
        f32x4 hi;
        hi.x = a1.w; hi.y = n1x; hi.z = n1y; hi.w = n1z;
        __builtin_nontemporal_store(hi, &d4[lane + 64]);
    }
    if (lane == 0) { dst[0] = a0.x; dst[1] = a0.y; dst[2] = a0.z; }
    if (last) dst[511] = a1.w;
}

// Parallel two-level descending select. Single block, 256 threads, all-parallel:
// level 1: pair-scan (Hillis-Steele) over 512 chunk sums in descending order;
// level 2: scan of the 128 bins inside the winning chunk. No serial rescans.
// pass 0: Kwant=K over hist1/chunk1 -> info[0]=bin1, info[1]=count_above.
// pass 1: Kwant=K-info[1] over hist2/chunk2 -> info[2]=thr key, info[3]=cnt>thr, info[4]=ties.
__global__ __launch_bounds__(256) void k_scan(const unsigned* __restrict__ hist,
                                              const unsigned* __restrict__ chunk,
                                              unsigned* __restrict__ info, int pass) {
    __shared__ unsigned ps[256];
    __shared__ unsigned s_chunk, s_above;
    int t = threadIdx.x;
    unsigned Kwant = (pass == 0) ? (unsigned)K_ : ((unsigned)K_ - info[1]);
    // level 1: elements i=2t,2t+1 in descending-chunk order
    unsigned a0 = chunk[511 - 2 * t];
    unsigned a1 = chunk[511 - (2 * t + 1)];
    unsigned pair = a0 + a1;
    ps[t] = pair;
    __syncthreads();
    #pragma unroll
    for (int off = 1; off < 256; off <<= 1) {
        unsigned v = (t >= off) ? ps[t - off] : 0u;
        __syncthreads();
        ps[t] += v;
        __syncthreads();
    }
    unsigned excl = ps[t] - pair;
    unsigned P0 = excl + a0;
    unsigned P1 = P0 + a1;
    if (excl < Kwant && P0 >= Kwant)      { s_chunk = 511u - 2u * t;       s_above = excl; }
    else if (P0 < Kwant && P1 >= Kwant)   { s_chunk = 511u - (2u * t + 1); s_above = P0; }
    __syncthreads();
    unsigned c = s_chunk, above = s_above;
    unsigned Kw2 = Kwant - above;
    // level 2: 128 bins of chunk c, descending
    unsigned b0 = (t < 128) ? hist[c * 128u + 127u - (unsigned)t] : 0u;
    ps[t] = b0;
    __syncthreads();
    #pragma unroll
    for (int off = 1; off < 128; off <<= 1) {
        unsigned v = (t >= off && t < 128) ? ps[t - off] : 0u;
        __syncthreads();
        if (t < 128) ps[t] += v;
        __syncthreads();
    }
    if (t < 128) {
        unsigned inc = ps[t], ex = inc - b0;
        if (ex < Kw2 && inc >= Kw2) {
            unsigned bin = c * 128u + 127u - (unsigned)t;
            unsigned cnt_above = above + ex;
            if (pass == 0) { info[0] = bin; info[1] = cnt_above; }
            else {
                info[2] = (info[0] << 16) | bin;
                info[3] = info[1] + cnt_above;
                info[4] = (unsigned)K_ - info[3];
            }
        }
    }
}

__global__ __launch_bounds__(256) void k_hist2(const float* __restrict__ alpha,
                                               const unsigned* __restrict__ info,
                                               unsigned* __restrict__ hist2,
                                               unsigned* __restrict__ chunk2) {
    int i = blockIdx.x * blockDim.x + threadIdx.x;
    unsigned key = fkey(alpha[i]);
    if ((key >> 16) == info[0]) {
        unsigned low = key & 0xFFFFu;
        atomicAdd(&hist2[low], 1u);
        atomicAdd(&chunk2[low >> 7], 1u);
    }
}

__global__ __launch_bounds__(256) void k_select(const float* __restrict__ alpha,
                                                const unsigned* __restrict__ info,
                                                unsigned* __restrict__ cnt,
                                                float* __restrict__ vals,
                                                int* __restrict__ idx) {
    int i = blockIdx.x * blockDim.x + threadIdx.x;
    float a = alpha[i];
    unsigned key = fkey(a);
    unsigned thr = info[2];
    if (key > thr) {
        unsigned p = atomicAdd(&cnt[0], 1u);
        vals[p] = a; idx[p] = i;
    } else if (key == thr) {
        unsigned t = atomicAdd(&cnt[1], 1u);
        if (t < info[4]) {
            unsigned p = info[3] + t;
            vals[p] = a; idx[p] = i;
        }
    }
}

// Fused softmax + attention gather. 128 blocks x 512 threads; each block
// redundantly computes softmax stats over the 1024 vals (L2-resident), then
// gathers its 8 rows into part[j] (deterministic fixed order).
__global__ __launch_bounds__(512) void k_attn(const float* __restrict__ hs,
                                              const float* __restrict__ vals,
                                              const int* __restrict__ idx,
                                              float* __restrict__ part) {
    __shared__ float red[512];
    int t = threadIdx.x, j = blockIdx.x;
    float v0 = vals[t], v1 = vals[t + 512];
    red[t] = fmaxf(v0, v1);
    __syncthreads();
    for (int s = 256; s > 0; s >>= 1) { if (t < s) red[t] = fmaxf(red[t], red[t + s]); __syncthreads(); }
    float m = red[0];
    __syncthreads();
    red[t] = expf(v0 - m) + expf(v1 - m);
    __syncthreads();
    for (int s = 256; s > 0; s >>= 1) { if (t < s) red[t] += red[t + s]; __syncthreads(); }
    float S = red[0];
    float acc = 0.f;
    #pragma unroll
    for (int k = j * 8; k < j * 8 + 8; ++k) {
        float w = expf(vals[k] - m) / S;
        acc = fmaf(w, hs[(size_t)idx[k] * E_ + t], acc);
    }
    part[(size_t)j * E_ + t] = acc;
}

// One wave per gate-row: gi = w_ih@x + b_ih, gh = w_hh@h + b_hh.
__global__ __launch_bounds__(256) void k_gru(const float* __restrict__ wih,
                                             const float* __restrict__ whh,
                                             const float* __restrict__ bih,
                                             const float* __restrict__ bhh,
                                             const float* __restrict__ ws_v,
                                             const float* __restrict__ score_s,
                                             const float* __restrict__ h_in,
                                             float* __restrict__ gi,
                                             float* __restrict__ gh) {
    __shared__ float x[1025 + 512];
    int t = threadIdx.x;
    float ss = score_s[0];
    float pos = ss >= 0.5f ? 1.f : 0.f;
    for (int c = t; c < 1025; c += 256) {
        float xv;
        if (c < 512)       xv = ws_v[c] * pos;
        else if (c < 1024) xv = ws_v[c - 512] * (1.f - pos);
        else               xv = ss;
        x[c] = xv;
    }
    for (int c = t; c < 512; c += 256) x[1025 + c] = h_in[c];
    __syncthreads();
    int wave = t >> 6, lane = t & 63;
    int row = blockIdx.x * 4 + wave;
    const float* wr = wih + (size_t)row * 1025;
    float s1 = 0.f;
    for (int c = lane; c < 1025; c += 64) s1 = fmaf(wr[c], x[c], s1);
    const float* hr = whh + (size_t)row * 512;
    float s2 = 0.f;
    #pragma unroll
    for (int c = lane; c < 512; c += 64) s2 = fmaf(hr[c], x[1025 + c], s2);
    #pragma unroll
    for (int m = 32; m; m >>= 1) {
        s1 += __shfl_xor(s1, m, 64);
        s2 += __shfl_xor(s2, m, 64);
    }
    if (lane == 0) { gi[row] = s1 + bih[row]; gh[row] = s2 + bhh[row]; }
}

// Fused GRU-finalize + score (one 512-thread block).
__global__ __launch_bounds__(512) void k_final(const float* __restrict__ gi,
                                               const float* __restrict__ gh,
                                               const float* __restrict__ h_in,
                                               const float* __restrict__ part,
                                               const float* __restrict__ ws_v,
                                               const float* __restrict__ w_score,
                                               const float* __restrict__ b_score,
                                               float* __restrict__ out) {
    __shared__ float red[512];
    int j = threadIdx.x;
    // GRU finalize
    float r = 1.f / (1.f + expf(-(gi[j] + gh[j])));
    float z = 1.f / (1.f + expf(-(gi[H_ + j] + gh[H_ + j])));
    float n = tanhf(gi[2 * H_ + j] + r * gh[2 * H_ + j]);
    float hp = h_in[j];
    float hn = (1.f - z) * n + z * hp;
    out[1 + j] = hn;                          // h_new
    out[OUT_HS + (size_t)T_ * E_ + j] = hn;   // hs_new last row
    // Score: reduce 128 attn partials, dot with w_score
    float attn = 0.f;
    for (int jj = 0; jj < 128; ++jj) attn += part[(size_t)jj * E_ + j];
    float d = ws_v[j] * w_score[j] + attn * w_score[512 + j] + hp * w_score[1024 + j];
    if (j == 0) d += 1024.0f * w_score[1536] + b_score[0];
    red[j] = d;
    __syncthreads();
    for (int s = 256; s > 0; s >>= 1) { if (j < s) red[j] += red[j + s]; __syncthreads(); }
    if (j == 0) out[0] = red[0];
}

extern "C" void kernel_launch(void* const* d_in, const int* in_sizes, int n_in,
                              void* d_out, int out_size, void* d_ws, size_t ws_size,
                              hipStream_t stream) {
    const int*   topic   = (const int*)d_in[0];
    const float* score_s = (const float*)d_in[1];
    const float* emb     = (const float*)d_in[2];
    const float* h_in    = (const float*)d_in[3];
    const float* vs      = (const float*)d_in[4];
    const float* hs      = (const float*)d_in[5];
    const float* w_ih    = (const float*)d_in[6];
    const float* w_hh    = (const float*)d_in[7];
    const float* b_ih    = (const float*)d_in[8];
    const float* b_hh    = (const float*)d_in[9];
    const float* w_score = (const float*)d_in[10];
    const float* b_score = (const float*)d_in[11];
    float* out = (float*)d_out;

    float*    wsf    = (float*)d_ws;
    float*    v_ws   = wsf + OFF_V;
    float*    alpha  = wsf + OFF_ALPHA;
    unsigned* hist1  = (unsigned*)(wsf + OFF_HIST1);
    unsigned* hist2  = (unsigned*)(wsf + OFF_HIST2);
    unsigned* cnt    = (unsigned*)(wsf + OFF_CNT);
    unsigned* info   = (unsigned*)(wsf + OFF_INFO);
    unsigned* chunk1 = (unsigned*)(wsf + OFF_CHUNK1);
    unsigned* chunk2 = (unsigned*)(wsf + OFF_CHUNK2);
    float*    vals   = wsf + OFF_VALS;
    int*      idx    = (int*)(wsf + OFF_IDX);
    float*    part   = wsf + OFF_ALPHA;  // alpha dead after k_select; reuse as partials
    float*    gi     = wsf + OFF_GI;
    float*    gh     = wsf + OFF_GH;

    // 1) v + zero-init (130 zero blocks cover ZERO_N, block 130 computes v)
    hipLaunchKernelGGL(k_init, dim3(131), dim3(1024), 0, stream,
                       topic, emb, v_ws, hist1, out);
    // 2) fused copies + alpha + hist1/chunk1
    hipLaunchKernelGGL(k_mega, dim3(2 * (T_ / 4)), dim3(256), 0, stream,
                       vs, hs, v_ws, alpha, hist1, chunk1, out);
    // 3-6) exact radix-select of top-K (parallel two-level scans)
    hipLaunchKernelGGL(k_scan, dim3(1), dim3(256), 0, stream, hist1, chunk1, info, 0);
    hipLaunchKernelGGL(k_hist2, dim3(T_ / 256), dim3(256), 0, stream, alpha, info, hist2, chunk2);
    hipLaunchKernelGGL(k_scan, dim3(1), dim3(256), 0, stream, hist2, chunk2, info, 1);
    hipLaunchKernelGGL(k_select, dim3(T_ / 256), dim3(256), 0, stream, alpha, info, cnt, vals, idx);
    // 7) fused softmax + attention gather (partials into dead alpha region)
    hipLaunchKernelGGL(k_attn, dim3(128), dim3(512), 0, stream, hs, vals, idx, part);
    // 8) GRU gates
    hipLaunchKernelGGL(k_gru, dim3(384), dim3(256), 0, stream,
                       w_ih, w_hh, b_ih, b_hh, v_ws, score_s, h_in, gi, gh);
    // 9) fused GRU-finalize + score
    hipLaunchKernelGGL(k_final, dim3(1), dim3(512), 0, stream,
                       gi, gh, h_in, part, v_ws, w_score, b_score, out);
}

// Round 5
// 244.903 us; speedup vs baseline: 3.5119x; 3.5119x over previous
//
#include <hip/hip_runtime.h>
#include <math.h>

// Problem constants (from reference)
constexpr int T_ = 131072;
constexpr int E_ = 512;
constexpr int H_ = 512;
constexpr int K_ = 1024;
constexpr int L_ = 128;

typedef __attribute__((ext_vector_type(4))) float f32x4;

// Workspace layout (element offsets; floats unless noted)
constexpr size_t OFF_V     = 0;                    // 512 f
constexpr size_t OFF_ALPHA = 512;                  // 131072 f (reused as attn partials)
constexpr size_t OFF_HIST1 = OFF_ALPHA + T_;       // 65536 u32
constexpr size_t OFF_HIST2 = OFF_HIST1 + 65536;    // 65536 u32
constexpr size_t OFF_CNT   = OFF_HIST2 + 65536;    // 2 u32
constexpr size_t OFF_INFO  = OFF_CNT + 2;          // 8 u32
constexpr size_t OFF_VALS  = OFF_INFO + 8;         // 1024 f
constexpr size_t OFF_IDX   = OFF_VALS + K_;        // 1024 i32
constexpr size_t OFF_GI    = OFF_IDX + K_;         // 1536 f
constexpr size_t OFF_GH    = OFF_GI + 3 * H_;      // 1536 f

// Zeroed-per-call contiguous region: hist1 + hist2 + cnt
constexpr int ZERO_N = 65536 + 65536 + 2;

// Output layout: score(1) | h_new(512) | vs_new((T+1)*512) | hs_new((T+1)*512)
constexpr size_t OUT_VS = 513;
constexpr size_t OUT_HS = 513 + (size_t)(T_ + 1) * E_;

__device__ __forceinline__ unsigned fkey(float f) {
    unsigned u = __float_as_uint(f);
    return (u & 0x80000000u) ? ~u : (u | 0x80000000u);  // ascending key == ascending float
}

// Last block: v = mean(emb[topic]) (two 512-thread halves, deterministic order).
// Other blocks: zero hist1+hist2+cnt (ZERO_N u32, contiguous).
__global__ __launch_bounds__(1024) void k_init(const int* __restrict__ topic,
                                               const float* __restrict__ emb,
                                               float* __restrict__ ws_v,
                                               unsigned* __restrict__ zero_base,
                                               float* __restrict__ out) {
    if (blockIdx.x == gridDim.x - 1) {
        __shared__ float part[512];
        int t = threadIdx.x;
        int e = t & 511, g = t >> 9;       // g in {0,1}
        float s = 0.f;
        #pragma unroll 8
        for (int l = g * 64; l < g * 64 + 64; ++l) {
            int tp = topic[l];
            s += emb[(size_t)tp * E_ + e];
        }
        if (g == 1) part[e] = s;
        __syncthreads();
        if (g == 0) {
            float v = (s + part[e]) * (1.0f / L_);
            ws_v[e] = v;
            out[OUT_VS + (size_t)T_ * E_ + e] = v;  // vs_new last row
        }
    } else {
        int i = blockIdx.x * blockDim.x + threadIdx.x;
        if (i < ZERO_N) zero_base[i] = 0u;
    }
}

// Mega kernel (REVERTED to R3 exactly): fused {vs copy + alpha dot + hist1}
// and {hs copy}. NT float4 streams; shuffle-rotate realignment for the
// 4B-misaligned output rows. ONE atomic per row to the 65536-bin hist
// (~170/bin contention — fine; NEVER add a low-cardinality counter here:
// R4's 512-entry chunk atomic serialized ~40K deep and cost 4x).
__global__ __launch_bounds__(256) void k_mega(const float* __restrict__ vs,
                                              const float* __restrict__ hs,
                                              const float* __restrict__ ws_v,
                                              float* __restrict__ alpha,
                                              unsigned* __restrict__ hist1,
                                              float* __restrict__ out) {
    int wave = threadIdx.x >> 6, lane = threadIdx.x & 63;
    int b = blockIdx.x;
    bool is_vs = b < (T_ / 4);
    int row = (is_vs ? b : b - T_ / 4) * 4 + wave;
    const f32x4* src4 = (const f32x4*)((is_vs ? vs : hs) + (size_t)row * E_);
    f32x4 a0 = __builtin_nontemporal_load(&src4[lane]);
    f32x4 a1 = __builtin_nontemporal_load(&src4[lane + 64]);
    if (is_vs) {
        const f32x4* v4 = (const f32x4*)ws_v;
        f32x4 b0 = v4[lane];
        f32x4 b1 = v4[lane + 64];
        float dot = 0.f;
        dot = fmaf(a0.x, b0.x, dot); dot = fmaf(a0.y, b0.y, dot);
        dot = fmaf(a0.z, b0.z, dot); dot = fmaf(a0.w, b0.w, dot);
        dot = fmaf(a1.x, b1.x, dot); dot = fmaf(a1.y, b1.y, dot);
        dot = fmaf(a1.z, b1.z, dot); dot = fmaf(a1.w, b1.w, dot);
        #pragma unroll
        for (int m = 32; m; m >>= 1) dot += __shfl_xor(dot, m, 64);
        if (lane == 0) {
            alpha[row] = dot;
            atomicAdd(&hist1[fkey(dot) >> 16], 1u);
        }
    }
    // Shuffle-rotate realignment
    int nl = (lane + 1) & 63;
    float n0x = __shfl(a0.x, nl, 64), n0y = __shfl(a0.y, nl, 64), n0z = __shfl(a0.z, nl, 64);
    float n1x = __shfl(a1.x, nl, 64), n1y = __shfl(a1.y, nl, 64), n1z = __shfl(a1.z, nl, 64);
    float* dst = out + (is_vs ? OUT_VS : OUT_HS) + (size_t)row * E_;
    f32x4* d4 = (f32x4*)(dst + 3);            // 16B-aligned
    bool last = (lane == 63);
    f32x4 lo;
    lo.x = a0.w;
    lo.y = last ? n1x : n0x;   // lane 63: e[256..258] = a1.xyz of lane 0
    lo.z = last ? n1y : n0y;
    lo.w = last ? n1z : n0z;
    __builtin_nontemporal_store(lo, &d4[lane]);
    if (!last) {
        f32x4 hi;
        hi.x = a1.w; hi.y = n1x; hi.z = n1y; hi.w = n1z;
        __builtin_nontemporal_store(hi, &d4[lane + 64]);
    }
    if (lane == 0) { dst[0] = a0.x; dst[1] = a0.y; dst[2] = a0.z; }
    if (last) dst[511] = a1.w;
}

// Fully-parallel descending select over a 65536-bin histogram. Single block,
// 256 threads. Phase 1: each thread sums its 256-bin chunk (descending chunk
// order, parallel — same as R3). Phase 2: 8-step Hillis-Steele scan over the
// 256 chunk sums (replaces R3's O(t) serial prefix). Phase 3: all threads
// load the winner chunk's 256 bins and scan again (replaces R3's serial
// 256-iteration dependent-load rescan). No global atomics.
__global__ __launch_bounds__(256) void k_scan(const unsigned* __restrict__ hist,
                                              unsigned* __restrict__ info, int pass) {
    __shared__ unsigned ps[256];
    __shared__ unsigned s_chunk, s_above;
    int t = threadIdx.x;
    unsigned Kwant = (pass == 0) ? (unsigned)K_ : ((unsigned)K_ - info[1]);
    // phase 1: chunk t covers bins [65536-256(t+1), 65536-256t)
    unsigned base = 65536u - (unsigned)(t + 1) * 256u;
    unsigned s = 0;
    for (int j = 0; j < 256; ++j) s += hist[base + j];
    ps[t] = s;
    __syncthreads();
    // phase 2: inclusive scan (descending-chunk prefix)
    #pragma unroll
    for (int off = 1; off < 256; off <<= 1) {
        unsigned v = (t >= off) ? ps[t - off] : 0u;
        __syncthreads();
        ps[t] += v;
        __syncthreads();
    }
    unsigned incl = ps[t], excl = incl - s;
    if (excl < Kwant && incl >= Kwant) { s_chunk = (unsigned)t; s_above = excl; }
    __syncthreads();
    unsigned c = s_chunk;
    unsigned Kw2 = Kwant - s_above;
    // phase 3: scan winner chunk's bins, descending: bin = 65535-256c-t
    unsigned bin = 65535u - c * 256u - (unsigned)t;
    unsigned b = hist[bin];
    __syncthreads();
    ps[t] = b;
    __syncthreads();
    #pragma unroll
    for (int off = 1; off < 256; off <<= 1) {
        unsigned v = (t >= off) ? ps[t - off] : 0u;
        __syncthreads();
        ps[t] += v;
        __syncthreads();
    }
    unsigned inc2 = ps[t], ex2 = inc2 - b;
    if (ex2 < Kw2 && inc2 >= Kw2) {
        unsigned cnt_above = s_above + ex2;
        if (pass == 0) { info[0] = bin; info[1] = cnt_above; }
        else {
            info[2] = (info[0] << 16) | bin;
            info[3] = info[1] + cnt_above;
            info[4] = (unsigned)K_ - info[3];
        }
    }
}

__global__ __launch_bounds__(256) void k_hist2(const float* __restrict__ alpha,
                                               const unsigned* __restrict__ info,
                                               unsigned* __restrict__ hist2) {
    int i = blockIdx.x * blockDim.x + threadIdx.x;
    unsigned key = fkey(alpha[i]);
    if ((key >> 16) == info[0]) atomicAdd(&hist2[key & 0xFFFFu], 1u);
}

__global__ __launch_bounds__(256) void k_select(const float* __restrict__ alpha,
                                                const unsigned* __restrict__ info,
                                                unsigned* __restrict__ cnt,
                                                float* __restrict__ vals,
                                                int* __restrict__ idx) {
    int i = blockIdx.x * blockDim.x + threadIdx.x;
    float a = alpha[i];
    unsigned key = fkey(a);
    unsigned thr = info[2];
    if (key > thr) {
        unsigned p = atomicAdd(&cnt[0], 1u);
        vals[p] = a; idx[p] = i;
    } else if (key == thr) {
        unsigned t = atomicAdd(&cnt[1], 1u);
        if (t < info[4]) {
            unsigned p = info[3] + t;
            vals[p] = a; idx[p] = i;
        }
    }
}

// Fused softmax + attention gather. 128 blocks x 512 threads; each block
// redundantly computes softmax stats over the 1024 vals (L2-resident), then
// gathers its 8 rows into part[j] (deterministic fixed order).
__global__ __launch_bounds__(512) void k_attn(const float* __restrict__ hs,
                                              const float* __restrict__ vals,
                                              const int* __restrict__ idx,
                                              float* __restrict__ part) {
    __shared__ float red[512];
    int t = threadIdx.x, j = blockIdx.x;
    float v0 = vals[t], v1 = vals[t + 512];
    red[t] = fmaxf(v0, v1);
    __syncthreads();
    for (int s = 256; s > 0; s >>= 1) { if (t < s) red[t] = fmaxf(red[t], red[t + s]); __syncthreads(); }
    float m = red[0];
    __syncthreads();
    red[t] = expf(v0 - m) + expf(v1 - m);
    __syncthreads();
    for (int s = 256; s > 0; s >>= 1) { if (t < s) red[t] += red[t + s]; __syncthreads(); }
    float S = red[0];
    float acc = 0.f;
    #pragma unroll
    for (int k = j * 8; k < j * 8 + 8; ++k) {
        float w = expf(vals[k] - m) / S;
        acc = fmaf(w, hs[(size_t)idx[k] * E_ + t], acc);
    }
    part[(size_t)j * E_ + t] = acc;
}

// One wave per gate-row: gi = w_ih@x + b_ih, gh = w_hh@h + b_hh.
__global__ __launch_bounds__(256) void k_gru(const float* __restrict__ wih,
                                             const float* __restrict__ whh,
                                             const float* __restrict__ bih,
                                             const float* __restrict__ bhh,
                                             const float* __restrict__ ws_v,
                                             const float* __restrict__ score_s,
                                             const float* __restrict__ h_in,
                                             float* __restrict__ gi,
                                             float* __restrict__ gh) {
    __shared__ float x[1025 + 512];
    int t = threadIdx.x;
    float ss = score_s[0];
    float pos = ss >= 0.5f ? 1.f : 0.f;
    for (int c = t; c < 1025; c += 256) {
        float xv;
        if (c < 512)       xv = ws_v[c] * pos;
        else if (c < 1024) xv = ws_v[c - 512] * (1.f - pos);
        else               xv = ss;
        x[c] = xv;
    }
    for (int c = t; c < 512; c += 256) x[1025 + c] = h_in[c];
    __syncthreads();
    int wave = t >> 6, lane = t & 63;
    int row = blockIdx.x * 4 + wave;
    const float* wr = wih + (size_t)row * 1025;
    float s1 = 0.f;
    for (int c = lane; c < 1025; c += 64) s1 = fmaf(wr[c], x[c], s1);
    const float* hr = whh + (size_t)row * 512;
    float s2 = 0.f;
    #pragma unroll
    for (int c = lane; c < 512; c += 64) s2 = fmaf(hr[c], x[1025 + c], s2);
    #pragma unroll
    for (int m = 32; m; m >>= 1) {
        s1 += __shfl_xor(s1, m, 64);
        s2 += __shfl_xor(s2, m, 64);
    }
    if (lane == 0) { gi[row] = s1 + bih[row]; gh[row] = s2 + bhh[row]; }
}

// Fused GRU-finalize + score (one 512-thread block).
__global__ __launch_bounds__(512) void k_final(const float* __restrict__ gi,
                                               const float* __restrict__ gh,
                                               const float* __restrict__ h_in,
                                               const float* __restrict__ part,
                                               const float* __restrict__ ws_v,
                                               const float* __restrict__ w_score,
                                               const float* __restrict__ b_score,
                                               float* __restrict__ out) {
    __shared__ float red[512];
    int j = threadIdx.x;
    // GRU finalize
    float r = 1.f / (1.f + expf(-(gi[j] + gh[j])));
    float z = 1.f / (1.f + expf(-(gi[H_ + j] + gh[H_ + j])));
    float n = tanhf(gi[2 * H_ + j] + r * gh[2 * H_ + j]);
    float hp = h_in[j];
    float hn = (1.f - z) * n + z * hp;
    out[1 + j] = hn;                          // h_new
    out[OUT_HS + (size_t)T_ * E_ + j] = hn;   // hs_new last row
    // Score: reduce 128 attn partials, dot with w_score
    float attn = 0.f;
    for (int jj = 0; jj < 128; ++jj) attn += part[(size_t)jj * E_ + j];
    float d = ws_v[j] * w_score[j] + attn * w_score[512 + j] + hp * w_score[1024 + j];
    if (j == 0) d += 1024.0f * w_score[1536] + b_score[0];
    red[j] = d;
    __syncthreads();
    for (int s = 256; s > 0; s >>= 1) { if (j < s) red[j] += red[j + s]; __syncthreads(); }
    if (j == 0) out[0] = red[0];
}

extern "C" void kernel_launch(void* const* d_in, const int* in_sizes, int n_in,
                              void* d_out, int out_size, void* d_ws, size_t ws_size,
                              hipStream_t stream) {
    const int*   topic   = (const int*)d_in[0];
    const float* score_s = (const float*)d_in[1];
    const float* emb     = (const float*)d_in[2];
    const float* h_in    = (const float*)d_in[3];
    const float* vs      = (const float*)d_in[4];
    const float* hs      = (const float*)d_in[5];
    const float* w_ih    = (const float*)d_in[6];
    const float* w_hh    = (const float*)d_in[7];
    const float* b_ih    = (const float*)d_in[8];
    const float* b_hh    = (const float*)d_in[9];
    const float* w_score = (const float*)d_in[10];
    const float* b_score = (const float*)d_in[11];
    float* out = (float*)d_out;

    float*    wsf   = (float*)d_ws;
    float*    v_ws  = wsf + OFF_V;
    float*    alpha = wsf + OFF_ALPHA;
    unsigned* hist1 = (unsigned*)(wsf + OFF_HIST1);
    unsigned* hist2 = (unsigned*)(wsf + OFF_HIST2);
    unsigned* cnt   = (unsigned*)(wsf + OFF_CNT);
    unsigned* info  = (unsigned*)(wsf + OFF_INFO);
    float*    vals  = wsf + OFF_VALS;
    int*      idx   = (int*)(wsf + OFF_IDX);
    float*    part  = wsf + OFF_ALPHA;  // alpha dead after k_select; reuse as partials
    float*    gi    = wsf + OFF_GI;
    float*    gh    = wsf + OFF_GH;

    // 1) v + zero-init (blocks 0..128 zero ZERO_N u32; block 129 computes v)
    hipLaunchKernelGGL(k_init, dim3(130), dim3(1024), 0, stream,
                       topic, emb, v_ws, hist1, out);
    // 2) fused copies + alpha + hist1
    hipLaunchKernelGGL(k_mega, dim3(2 * (T_ / 4)), dim3(256), 0, stream,
                       vs, hs, v_ws, alpha, hist1, out);
    // 3-6) exact radix-select of top-K (fully parallel scans, no new atomics)
    hipLaunchKernelGGL(k_scan, dim3(1), dim3(256), 0, stream, hist1, info, 0);
    hipLaunchKernelGGL(k_hist2, dim3(T_ / 256), dim3(256), 0, stream, alpha, info, hist2);
    hipLaunchKernelGGL(k_scan, dim3(1), dim3(256), 0, stream, hist2, info, 1);
    hipLaunchKernelGGL(k_select, dim3(T_ / 256), dim3(256), 0, stream, alpha, info, cnt, vals, idx);
    // 7) fused softmax + attention gather (partials into dead alpha region)
    hipLaunchKernelGGL(k_attn, dim3(128), dim3(512), 0, stream, hs, vals, idx, part);
    // 8) GRU gates
    hipLaunchKernelGGL(k_gru, dim3(384), dim3(256), 0, stream,
                       w_ih, w_hh, b_ih, b_hh, v_ws, score_s, h_in, gi, gh);
    // 9) fused GRU-finalize + score
    hipLaunchKernelGGL(k_final, dim3(1), dim3(512), 0, stream,
                       gi, gh, h_in, part, v_ws, w_score, b_score, out);
}